// Round 16
// baseline (133.563 us; speedup 1.0000x reference)
//
#include <hip/hip_runtime.h>
#include <stdint.h>

// CDSSM: conv1(128ch,k3) -> tanh -> conv2(128ch,k3) -> tanh -> max_t -> proj -> tanh
//        then dots(q·pos, q·negs) -> gamma -> softmax.  B=64,T=2048,D=K=K2=128,L=64,J=2.
// R16: R15 (131.2us: single-pass 256 blocks, wave-specialized 4+4, taps 0,1 pinned,
//      tap2 transient, pre-tanh max, 1 barrier/iter, setprio, fused k2) + k3 fused
//      via last-block pattern (prep zeroes counter; 256th block runs dots+softmax).
//      Saves the k3 launch/graph node. Everything else byte-identical to R15.

typedef __bf16 bf16x8 __attribute__((ext_vector_type(8)));
typedef __bf16 bf16x4 __attribute__((ext_vector_type(4)));
typedef float f32x16 __attribute__((ext_vector_type(16)));
typedef unsigned short u16x8 __attribute__((ext_vector_type(8)));

__device__ __forceinline__ unsigned short f2bf(float f) {
  unsigned u = __builtin_bit_cast(unsigned, f);
  u = u + 0x7FFFu + ((u >> 16) & 1u);   // RTNE
  return (unsigned short)(u >> 16);
}

__device__ __forceinline__ float fast_tanh(float x) {
  x = fminf(10.0f, fmaxf(-10.0f, x));
  float t = __builtin_amdgcn_exp2f(x * -2.8853900817779268f);   // e^{-2x}
  return (1.0f - t) * __builtin_amdgcn_rcpf(1.0f + t);
}

// ---------------- prep: fp32 [k][d][f] -> bf16 fragment-major [br][f][kk][row][hi][j] ----------------
__global__ void prep_kernel(const float* __restrict__ qw1, const float* __restrict__ qw2,
                            const float* __restrict__ dw1, const float* __restrict__ dw2,
                            unsigned short* __restrict__ W1f, unsigned short* __restrict__ W2f,
                            unsigned* __restrict__ counter) {
  int gid = blockIdx.x * 256 + threadIdx.x;          // 768*256 = 196608 exact
  if (gid == 0) *counter = 0u;                       // reset tail-block ticket each call
  int which = gid >= 98304;                          // 0: W1f, 1: W2f
  int e = which ? gid - 98304 : gid;
  int br = e / 49152; int r = e % 49152;
  int f = r / 16384; int r2 = r & 16383;
  int kk = r2 >> 11; int row = (r2 >> 4) & 127; int hi = (r2 >> 3) & 1; int j = r2 & 7;
  int c = kk * 16 + hi * 8 + j;
  const float* src = which ? (br ? dw2 : qw2) : (br ? dw1 : qw1);
  (which ? W2f : W1f)[e] = f2bf(src[row * 384 + c * 3 + f]);
}

// ---------------- main fused conv kernel ----------------
// LDS (dynamic, 65024 B):
//  XS0  0     : bf16 [2 buf][64 slot][128 d], swizzled  (32768)
//  H1S0 32768 : bf16 [2 buf][62 slot][128 k], swizzled  (31744)
//  B1   64512 : float[128] bias1                        (512)
#define XS0    0
#define XBUF   16384
#define H1S0   32768
#define HBUF   15872
#define B1_OFF 64512
#define LDS_TOTAL 65024
#define YS 60          // fresh conv2 outputs per window
#define NWIN 35        // ceil(2044/60)
#define TOUT 2044      // total valid conv2 outputs per sequence

__global__ __launch_bounds__(512) void cdssm_main(
    const float* __restrict__ q, const float* __restrict__ pos, const float* __restrict__ negs,
    const unsigned short* __restrict__ W1f, const unsigned short* __restrict__ W2f,
    const float* __restrict__ qb1, const float* __restrict__ db1,
    const float* __restrict__ qb2, const float* __restrict__ db2,
    const float* __restrict__ qsw, const float* __restrict__ qsb,
    const float* __restrict__ dsw, const float* __restrict__ dsb,
    const float* __restrict__ gw, const float* __restrict__ gb,
    float* __restrict__ s_out, unsigned* __restrict__ counter,
    float* __restrict__ out) {
  extern __shared__ char lds[];
  const int tid = threadIdx.x;
  const int seq = blockIdx.x;         // 256 blocks = 1 per sequence
  const int branch = (seq < 64) ? 0 : 1;
  const float* xptr = (seq < 64) ? (q + (size_t)seq * 2048 * 128)
                    : (seq < 128) ? (pos + (size_t)(seq - 64) * 2048 * 128)
                                  : (negs + (size_t)(seq - 128) * 2048 * 128);
  const float* b1g = branch ? db1 : qb1;

  if (tid < 128) ((float*)(lds + B1_OFF))[tid] = b1g[tid];

  const int lane = tid & 63;
  const int w = tid >> 6;            // 8 waves
  const int lrow = lane & 31;
  const int hi5 = lane >> 5;
  const int role = w >> 2;           // 0 = conv1 waves, 1 = conv2 waves
  const int kt = w & 3;              // k-tile: output rows [kt*32, kt*32+32)
  const int hi16 = hi5 * 16;

  // fragment-major base for THIS wave's k-tile; frag = wfb + f*16384 + kk*2048
  const unsigned short* wfb = (role ? W2f : W1f) + (size_t)branch * 49152
                              + (kt * 32 + lrow) * 16 + hi5 * 8;

  // pin taps 0,1 (64 VGPRs); tap 2 loaded transient per use
  bf16x8 ap[16];
#pragma unroll
  for (int f = 0; f < 2; ++f)
#pragma unroll
    for (int kk = 0; kk < 8; ++kk)
      ap[f * 8 + kk] = __builtin_bit_cast(bf16x8,
          *(const u16x8*)(wfb + f * 16384 + kk * 2048));

  float vmax[16];
#pragma unroll
  for (int r = 0; r < 16; ++r) vmax[r] = -1e30f;

  // staging geometry: 1024 chunks (64 slots x 16), 2 per thread (slot_s, slot_s+32)
  const int slot_s = tid >> 4;
  const int d0_s = (tid & 15) * 8;

  // ---- prologue: stage X window 0 into Xbuf0 ----
#pragma unroll
  for (int u = 0; u < 2; ++u) {
    int sl = slot_s + u * 32;
    int t = sl;                          // lo = 0
    const float* src = xptr + ((size_t)t * 128 + d0_s);
    float4 v0 = *(const float4*)src;
    float4 v1 = *(const float4*)(src + 4);
    bf16x8 o;
    o[0] = (__bf16)v0.x; o[1] = (__bf16)v0.y; o[2] = (__bf16)v0.z; o[3] = (__bf16)v0.w;
    o[4] = (__bf16)v1.x; o[5] = (__bf16)v1.y; o[6] = (__bf16)v1.z; o[7] = (__bf16)v1.w;
    *(bf16x8*)(lds + XS0 + sl * 256 + ((d0_s * 2) ^ ((sl & 15) << 4))) = o;
  }
  __syncthreads();   // X(0) + bias + pinned weights ready

  for (int i = 0; i <= NWIN; ++i) {
    // ---- issue staging loads for window i+1 (hide HBM under compute) ----
    float4 va[4];
    const bool doStage = (i < NWIN - 1);
    if (doStage) {
      const int tb = (i + 1) * YS;
#pragma unroll
      for (int u = 0; u < 2; ++u) {
        int t = tb + slot_s + u * 32; if (t > 2047) t = 2047;
        const float* src = xptr + ((size_t)t * 128 + d0_s);
        va[2 * u]     = *(const float4*)src;
        va[2 * u + 1] = *(const float4*)(src + 4);
      }
    }

    if (role == 0) {
      // ---- conv1 wave: compute h1 window i (2 panels) into h1buf[i&1] ----
      if (i < NWIN) {
        const int xb = XS0 + (i & 1) * XBUF;
        f32x16 acc0, acc1;
#pragma unroll
        for (int r = 0; r < 16; ++r) { acc0[r] = 0.f; acc1[r] = 0.f; }
        __builtin_amdgcn_s_setprio(1);
#pragma unroll
        for (int f = 0; f < 2; ++f) {
          int sv0 = lrow + f;                              // <= 33, no clamp
          int sv1 = 32 + lrow + f; if (sv1 > 63) sv1 = 63; // cols 62,63 garbage
          int b0 = xb + sv0 * 256, z0 = (sv0 & 15) << 4;
          int b1 = xb + sv1 * 256, z1 = (sv1 & 15) << 4;
#pragma unroll
          for (int kk = 0; kk < 8; ++kk) {
            int ko = kk * 32 + hi16;
            bf16x8 bv0 = __builtin_bit_cast(bf16x8,
                *(const u16x8*)(lds + b0 + (ko ^ z0)));
            acc0 = __builtin_amdgcn_mfma_f32_32x32x16_bf16(ap[f * 8 + kk], bv0, acc0, 0, 0, 0);
            bf16x8 bv1 = __builtin_bit_cast(bf16x8,
                *(const u16x8*)(lds + b1 + (ko ^ z1)));
            acc1 = __builtin_amdgcn_mfma_f32_32x32x16_bf16(ap[f * 8 + kk], bv1, acc1, 0, 0, 0);
          }
        }
        {   // tap 2 transient (shared across both panels)
          int sv0 = lrow + 2;
          int sv1 = 32 + lrow + 2; if (sv1 > 63) sv1 = 63;
          int b0 = xb + sv0 * 256, z0 = (sv0 & 15) << 4;
          int b1 = xb + sv1 * 256, z1 = (sv1 & 15) << 4;
#pragma unroll
          for (int kk = 0; kk < 8; ++kk) {
            bf16x8 av = __builtin_bit_cast(bf16x8,
                *(const u16x8*)(wfb + 2 * 16384 + kk * 2048));
            int ko = kk * 32 + hi16;
            bf16x8 bv0 = __builtin_bit_cast(bf16x8,
                *(const u16x8*)(lds + b0 + (ko ^ z0)));
            acc0 = __builtin_amdgcn_mfma_f32_32x32x16_bf16(av, bv0, acc0, 0, 0, 0);
            bf16x8 bv1 = __builtin_bit_cast(bf16x8,
                *(const u16x8*)(lds + b1 + (ko ^ z1)));
            acc1 = __builtin_amdgcn_mfma_f32_32x32x16_bf16(av, bv1, acc1, 0, 0, 0);
          }
        }
        __builtin_amdgcn_s_setprio(0);
        // epilogue: bias1 + tanh -> h1 (cols 0..61 valid)
        const int hb = H1S0 + (i & 1) * HBUF;
#pragma unroll
        for (int p = 0; p < 2; ++p) {
          const f32x16 acc = p ? acc1 : acc0;
          int s = p * 32 + lrow;
          if (s < 62) {
            int wb2 = hb + s * 256;
            int wz = (s & 15) << 4;
#pragma unroll
            for (int qd = 0; qd < 4; ++qd) {
              int k0 = kt * 32 + qd * 8 + hi5 * 4;   // C rows: (reg&3)+8*(reg>>2)+4*hi
              float4 bq = *(const float4*)(lds + B1_OFF + k0 * 4);
              bf16x4 hv;
              hv[0] = (__bf16)fast_tanh(acc[qd * 4 + 0] + bq.x);
              hv[1] = (__bf16)fast_tanh(acc[qd * 4 + 1] + bq.y);
              hv[2] = (__bf16)fast_tanh(acc[qd * 4 + 2] + bq.z);
              hv[3] = (__bf16)fast_tanh(acc[qd * 4 + 3] + bq.w);
              *(bf16x4*)(lds + wb2 + ((k0 * 2) ^ wz)) = hv;
            }
          }
        }
      }
    } else {
      // ---- conv2 wave: consume h1 window i-1 (2 panels) from h1buf[(i&1)^1] ----
      if (i >= 1) {
        const int hb = H1S0 + ((i & 1) ^ 1) * HBUF;
        f32x16 acc0, acc1;
#pragma unroll
        for (int r = 0; r < 16; ++r) { acc0[r] = 0.f; acc1[r] = 0.f; }
        __builtin_amdgcn_s_setprio(1);
#pragma unroll
        for (int f = 0; f < 2; ++f) {
          int sv0 = lrow + f;                              // <= 33
          int sv1 = 32 + lrow + f; if (sv1 > 61) sv1 = 61;
          int b0 = hb + sv0 * 256, z0 = (sv0 & 15) << 4;
          int b1 = hb + sv1 * 256, z1 = (sv1 & 15) << 4;
#pragma unroll
          for (int kk = 0; kk < 8; ++kk) {
            int ko = kk * 32 + hi16;
            bf16x8 bv0 = __builtin_bit_cast(bf16x8,
                *(const u16x8*)(lds + b0 + (ko ^ z0)));
            acc0 = __builtin_amdgcn_mfma_f32_32x32x16_bf16(ap[f * 8 + kk], bv0, acc0, 0, 0, 0);
            bf16x8 bv1 = __builtin_bit_cast(bf16x8,
                *(const u16x8*)(lds + b1 + (ko ^ z1)));
            acc1 = __builtin_amdgcn_mfma_f32_32x32x16_bf16(ap[f * 8 + kk], bv1, acc1, 0, 0, 0);
          }
        }
        {   // tap 2 transient
          int sv0 = lrow + 2;
          int sv1 = 32 + lrow + 2; if (sv1 > 61) sv1 = 61;
          int b0 = hb + sv0 * 256, z0 = (sv0 & 15) << 4;
          int b1 = hb + sv1 * 256, z1 = (sv1 & 15) << 4;
#pragma unroll
          for (int kk = 0; kk < 8; ++kk) {
            bf16x8 av = __builtin_bit_cast(bf16x8,
                *(const u16x8*)(wfb + 2 * 16384 + kk * 2048));
            int ko = kk * 32 + hi16;
            bf16x8 bv0 = __builtin_bit_cast(bf16x8,
                *(const u16x8*)(lds + b0 + (ko ^ z0)));
            acc0 = __builtin_amdgcn_mfma_f32_32x32x16_bf16(av, bv0, acc0, 0, 0, 0);
            bf16x8 bv1 = __builtin_bit_cast(bf16x8,
                *(const u16x8*)(lds + b1 + (ko ^ z1)));
            acc1 = __builtin_amdgcn_mfma_f32_32x32x16_bf16(av, bv1, acc1, 0, 0, 0);
          }
        }
        __builtin_amdgcn_s_setprio(0);
        // epilogue: running PRE-TANH max, both panels fold into vmax[16]
        const int base = (i - 1) * YS;
        const bool valid0 = (base + lrow < TOUT);            // lrow < 60 always
        const int s2b = 32 + lrow;
        const bool valid1 = (s2b < YS) && (base + s2b < TOUT);
#pragma unroll
        for (int r = 0; r < 16; ++r) {
          float v0 = valid0 ? acc0[r] : -1e30f;
          float v1 = valid1 ? acc1[r] : -1e30f;
          vmax[r] = fmaxf(vmax[r], fmaxf(v0, v1));
        }
      }
    }

    // ---- convert + write staged X window i+1 into Xbuf[(i+1)&1] ----
    if (doStage) {
      const int xbn = XS0 + ((i + 1) & 1) * XBUF;
#pragma unroll
      for (int u = 0; u < 2; ++u) {
        int sl = slot_s + u * 32;
        const float* f0 = (const float*)&va[2 * u];
        bf16x8 o;
#pragma unroll
        for (int j = 0; j < 8; ++j) o[j] = (__bf16)f0[j];
        *(bf16x8*)(lds + xbn + sl * 256 + ((d0_s * 2) ^ ((sl & 15) << 4))) = o;
      }
    }
    __syncthreads();
  }

  // ---- final: conv2 waves reduce vmax across their 32 columns ----
  if (role == 1) {
#pragma unroll
    for (int r = 0; r < 16; ++r) {
      float v = vmax[r];
      v = fmaxf(v, __shfl_xor(v, 1, 64));
      v = fmaxf(v, __shfl_xor(v, 2, 64));
      v = fmaxf(v, __shfl_xor(v, 4, 64));
      v = fmaxf(v, __shfl_xor(v, 8, 64));
      v = fmaxf(v, __shfl_xor(v, 16, 64));
      vmax[r] = v;
    }
  }
  float* hbuf = (float*)(lds + XS0);   // X buffers dead now
  if (role == 1 && lrow == 0) {
#pragma unroll
    for (int r = 0; r < 16; ++r) {
      int rl = (r & 3) + 8 * (r >> 2) + 4 * hi5;
      hbuf[kt * 32 + rl] = vmax[r];
    }
  }
  __syncthreads();

  // ---- fused k2: bias2 + tanh, then 64x128 projection + tanh -> s_out ----
  float* htan = hbuf + 128;
  if (tid < 128) {
    const float* b2 = branch ? db2 : qb2;
    htan[tid] = fast_tanh(hbuf[tid] + b2[tid]);
  }
  __syncthreads();
  if (tid < 64) {
    const float* sw = branch ? dsw : qsw;
    const float* sb = branch ? dsb : qsb;
    float acc = sb[tid];
#pragma unroll
    for (int k = 0; k < 128; k += 4) {
      float4 wv = *(const float4*)(sw + tid * 128 + k);
      acc += htan[k] * wv.x + htan[k + 1] * wv.y + htan[k + 2] * wv.z + htan[k + 3] * wv.w;
    }
    s_out[(size_t)seq * 64 + tid] = fast_tanh(acc);
  }

  // ---- fused k3 (last-block): dots, gamma, softmax ----
  __syncthreads();   // s_out stores issued and drained (barrier implies vmcnt drain)
  int* lflag = (int*)(lds + B1_OFF);   // bias1 region dead now
  if (tid == 0) {
    __threadfence();                       // release: publish s_out across XCDs
    unsigned old = atomicAdd(counter, 1u); // device-scope ticket
    *lflag = (old == 255u) ? 1 : 0;
  }
  __syncthreads();
  if (*lflag) {
    __threadfence();                       // acquire: see all blocks' s_out
    if (tid < 64) {
      int b = tid;
      const float* qs = s_out + (size_t)b * 64;
      const float* ps = s_out + (size_t)(64 + b) * 64;
      const float* n0 = s_out + (size_t)(128 + b) * 64;
      const float* n1 = s_out + (size_t)(192 + b) * 64;
      float d0 = 0.f, d1 = 0.f, d2 = 0.f;
      for (int l = 0; l < 64; ++l) {
        float v = qs[l];
        d0 += v * ps[l];
        d1 += v * n0[l];
        d2 += v * n1[l];
      }
      float g = gw[0], bb = gb[0];
      d0 = g * d0 + bb; d1 = g * d1 + bb; d2 = g * d2 + bb;
      float m = fmaxf(d0, fmaxf(d1, d2));
      float e0 = expf(d0 - m), e1 = expf(d1 - m), e2 = expf(d2 - m);
      float inv = 1.0f / (e0 + e1 + e2);
      out[b * 3 + 0] = e0 * inv;
      out[b * 3 + 1] = e1 * inv;
      out[b * 3 + 2] = e2 * inv;
    }
  }
}

extern "C" void kernel_launch(void* const* d_in, const int* in_sizes, int n_in,
                              void* d_out, int out_size, void* d_ws, size_t ws_size,
                              hipStream_t stream) {
  const float* q    = (const float*)d_in[0];
  const float* pos  = (const float*)d_in[1];
  const float* negs = (const float*)d_in[2];
  const float* qw1  = (const float*)d_in[3];
  const float* qb1  = (const float*)d_in[4];
  const float* qw2  = (const float*)d_in[5];
  const float* qb2  = (const float*)d_in[6];
  const float* qsw  = (const float*)d_in[7];
  const float* qsb  = (const float*)d_in[8];
  const float* dw1  = (const float*)d_in[9];
  const float* db1  = (const float*)d_in[10];
  const float* dw2  = (const float*)d_in[11];
  const float* db2  = (const float*)d_in[12];
  const float* dsw  = (const float*)d_in[13];
  const float* dsb  = (const float*)d_in[14];
  const float* gw   = (const float*)d_in[15];
  const float* gb   = (const float*)d_in[16];
  float* out = (float*)d_out;

  char* ws = (char*)d_ws;
  unsigned short* W1f = (unsigned short*)(ws);             // 98304 elems = 196608 B
  unsigned short* W2f = (unsigned short*)(ws + 196608);    // 98304 elems = 196608 B
  float* s_out        = (float*)(ws + 393216);             // 256*64*4 = 65536 B
  unsigned* counter   = (unsigned*)(ws + 458752);          // 4 B tail-block ticket

  hipFuncSetAttribute((const void*)cdssm_main,
                      hipFuncAttributeMaxDynamicSharedMemorySize, LDS_TOTAL);

  prep_kernel<<<768, 256, 0, stream>>>(qw1, qw2, dw1, dw2, W1f, W2f, counter);
  cdssm_main<<<256, 512, LDS_TOTAL, stream>>>(q, pos, negs, W1f, W2f, qb1, db1,
                                              qb2, db2, qsw, qsb, dsw, dsb,
                                              gw, gb, s_out, counter, out);
}

// Round 17
// 130.796 us; speedup vs baseline: 1.0212x; 1.0212x over previous
//
#include <hip/hip_runtime.h>
#include <stdint.h>

// CDSSM: conv1(128ch,k3) -> tanh -> conv2(128ch,k3) -> tanh -> max_t -> proj -> tanh
//        then dots(q·pos, q·negs) -> gamma -> softmax.  B=64,T=2048,D=K=K2=128,L=64,J=2.
// R17 = R15 reverted (measured best: 131.2us). R16's last-block k3 fusion was
//      neutral-negative -> dropped. Structure: single-pass 256 blocks, wave-specialized
//      4 conv1 + 4 conv2 waves, taps 0,1 pinned in 64 VGPR, tap2 transient, 2 panels
//      per wave, pre-tanh running max, 1 barrier/iter, setprio, fused k2 epilogue.

typedef __bf16 bf16x8 __attribute__((ext_vector_type(8)));
typedef __bf16 bf16x4 __attribute__((ext_vector_type(4)));
typedef float f32x16 __attribute__((ext_vector_type(16)));
typedef unsigned short u16x8 __attribute__((ext_vector_type(8)));

__device__ __forceinline__ unsigned short f2bf(float f) {
  unsigned u = __builtin_bit_cast(unsigned, f);
  u = u + 0x7FFFu + ((u >> 16) & 1u);   // RTNE
  return (unsigned short)(u >> 16);
}

__device__ __forceinline__ float fast_tanh(float x) {
  x = fminf(10.0f, fmaxf(-10.0f, x));
  float t = __builtin_amdgcn_exp2f(x * -2.8853900817779268f);   // e^{-2x}
  return (1.0f - t) * __builtin_amdgcn_rcpf(1.0f + t);
}

// ---------------- prep: fp32 [k][d][f] -> bf16 fragment-major [br][f][kk][row][hi][j] ----------------
__global__ void prep_kernel(const float* __restrict__ qw1, const float* __restrict__ qw2,
                            const float* __restrict__ dw1, const float* __restrict__ dw2,
                            unsigned short* __restrict__ W1f, unsigned short* __restrict__ W2f) {
  int gid = blockIdx.x * 256 + threadIdx.x;          // 768*256 = 196608 exact
  int which = gid >= 98304;                          // 0: W1f, 1: W2f
  int e = which ? gid - 98304 : gid;
  int br = e / 49152; int r = e % 49152;
  int f = r / 16384; int r2 = r & 16383;
  int kk = r2 >> 11; int row = (r2 >> 4) & 127; int hi = (r2 >> 3) & 1; int j = r2 & 7;
  int c = kk * 16 + hi * 8 + j;
  const float* src = which ? (br ? dw2 : qw2) : (br ? dw1 : qw1);
  (which ? W2f : W1f)[e] = f2bf(src[row * 384 + c * 3 + f]);
}

// ---------------- main fused conv kernel ----------------
// LDS (dynamic, 65024 B):
//  XS0  0     : bf16 [2 buf][64 slot][128 d], swizzled  (32768)
//  H1S0 32768 : bf16 [2 buf][62 slot][128 k], swizzled  (31744)
//  B1   64512 : float[128] bias1                        (512)
#define XS0    0
#define XBUF   16384
#define H1S0   32768
#define HBUF   15872
#define B1_OFF 64512
#define LDS_TOTAL 65024
#define YS 60          // fresh conv2 outputs per window
#define NWIN 35        // ceil(2044/60)
#define TOUT 2044      // total valid conv2 outputs per sequence

__global__ __launch_bounds__(512) void cdssm_main(
    const float* __restrict__ q, const float* __restrict__ pos, const float* __restrict__ negs,
    const unsigned short* __restrict__ W1f, const unsigned short* __restrict__ W2f,
    const float* __restrict__ qb1, const float* __restrict__ db1,
    const float* __restrict__ qb2, const float* __restrict__ db2,
    const float* __restrict__ qsw, const float* __restrict__ qsb,
    const float* __restrict__ dsw, const float* __restrict__ dsb,
    float* __restrict__ s_out) {
  extern __shared__ char lds[];
  const int tid = threadIdx.x;
  const int seq = blockIdx.x;         // 256 blocks = 1 per sequence
  const int branch = (seq < 64) ? 0 : 1;
  const float* xptr = (seq < 64) ? (q + (size_t)seq * 2048 * 128)
                    : (seq < 128) ? (pos + (size_t)(seq - 64) * 2048 * 128)
                                  : (negs + (size_t)(seq - 128) * 2048 * 128);
  const float* b1g = branch ? db1 : qb1;

  if (tid < 128) ((float*)(lds + B1_OFF))[tid] = b1g[tid];

  const int lane = tid & 63;
  const int w = tid >> 6;            // 8 waves
  const int lrow = lane & 31;
  const int hi5 = lane >> 5;
  const int role = w >> 2;           // 0 = conv1 waves, 1 = conv2 waves
  const int kt = w & 3;              // k-tile: output rows [kt*32, kt*32+32)
  const int hi16 = hi5 * 16;

  // fragment-major base for THIS wave's k-tile; frag = wfb + f*16384 + kk*2048
  const unsigned short* wfb = (role ? W2f : W1f) + (size_t)branch * 49152
                              + (kt * 32 + lrow) * 16 + hi5 * 8;

  // pin taps 0,1 (64 VGPRs); tap 2 loaded transient per use
  bf16x8 ap[16];
#pragma unroll
  for (int f = 0; f < 2; ++f)
#pragma unroll
    for (int kk = 0; kk < 8; ++kk)
      ap[f * 8 + kk] = __builtin_bit_cast(bf16x8,
          *(const u16x8*)(wfb + f * 16384 + kk * 2048));

  float vmax[16];
#pragma unroll
  for (int r = 0; r < 16; ++r) vmax[r] = -1e30f;

  // staging geometry: 1024 chunks (64 slots x 16), 2 per thread (slot_s, slot_s+32)
  const int slot_s = tid >> 4;
  const int d0_s = (tid & 15) * 8;

  // ---- prologue: stage X window 0 into Xbuf0 ----
#pragma unroll
  for (int u = 0; u < 2; ++u) {
    int sl = slot_s + u * 32;
    int t = sl;                          // lo = 0
    const float* src = xptr + ((size_t)t * 128 + d0_s);
    float4 v0 = *(const float4*)src;
    float4 v1 = *(const float4*)(src + 4);
    bf16x8 o;
    o[0] = (__bf16)v0.x; o[1] = (__bf16)v0.y; o[2] = (__bf16)v0.z; o[3] = (__bf16)v0.w;
    o[4] = (__bf16)v1.x; o[5] = (__bf16)v1.y; o[6] = (__bf16)v1.z; o[7] = (__bf16)v1.w;
    *(bf16x8*)(lds + XS0 + sl * 256 + ((d0_s * 2) ^ ((sl & 15) << 4))) = o;
  }
  __syncthreads();   // X(0) + bias + pinned weights ready

  for (int i = 0; i <= NWIN; ++i) {
    // ---- issue staging loads for window i+1 (hide HBM under compute) ----
    float4 va[4];
    const bool doStage = (i < NWIN - 1);
    if (doStage) {
      const int tb = (i + 1) * YS;
#pragma unroll
      for (int u = 0; u < 2; ++u) {
        int t = tb + slot_s + u * 32; if (t > 2047) t = 2047;
        const float* src = xptr + ((size_t)t * 128 + d0_s);
        va[2 * u]     = *(const float4*)src;
        va[2 * u + 1] = *(const float4*)(src + 4);
      }
    }

    if (role == 0) {
      // ---- conv1 wave: compute h1 window i (2 panels) into h1buf[i&1] ----
      if (i < NWIN) {
        const int xb = XS0 + (i & 1) * XBUF;
        f32x16 acc0, acc1;
#pragma unroll
        for (int r = 0; r < 16; ++r) { acc0[r] = 0.f; acc1[r] = 0.f; }
        __builtin_amdgcn_s_setprio(1);
#pragma unroll
        for (int f = 0; f < 2; ++f) {
          int sv0 = lrow + f;                              // <= 33, no clamp
          int sv1 = 32 + lrow + f; if (sv1 > 63) sv1 = 63; // cols 62,63 garbage
          int b0 = xb + sv0 * 256, z0 = (sv0 & 15) << 4;
          int b1 = xb + sv1 * 256, z1 = (sv1 & 15) << 4;
#pragma unroll
          for (int kk = 0; kk < 8; ++kk) {
            int ko = kk * 32 + hi16;
            bf16x8 bv0 = __builtin_bit_cast(bf16x8,
                *(const u16x8*)(lds + b0 + (ko ^ z0)));
            acc0 = __builtin_amdgcn_mfma_f32_32x32x16_bf16(ap[f * 8 + kk], bv0, acc0, 0, 0, 0);
            bf16x8 bv1 = __builtin_bit_cast(bf16x8,
                *(const u16x8*)(lds + b1 + (ko ^ z1)));
            acc1 = __builtin_amdgcn_mfma_f32_32x32x16_bf16(ap[f * 8 + kk], bv1, acc1, 0, 0, 0);
          }
        }
        {   // tap 2 transient (shared across both panels)
          int sv0 = lrow + 2;
          int sv1 = 32 + lrow + 2; if (sv1 > 63) sv1 = 63;
          int b0 = xb + sv0 * 256, z0 = (sv0 & 15) << 4;
          int b1 = xb + sv1 * 256, z1 = (sv1 & 15) << 4;
#pragma unroll
          for (int kk = 0; kk < 8; ++kk) {
            bf16x8 av = __builtin_bit_cast(bf16x8,
                *(const u16x8*)(wfb + 2 * 16384 + kk * 2048));
            int ko = kk * 32 + hi16;
            bf16x8 bv0 = __builtin_bit_cast(bf16x8,
                *(const u16x8*)(lds + b0 + (ko ^ z0)));
            acc0 = __builtin_amdgcn_mfma_f32_32x32x16_bf16(av, bv0, acc0, 0, 0, 0);
            bf16x8 bv1 = __builtin_bit_cast(bf16x8,
                *(const u16x8*)(lds + b1 + (ko ^ z1)));
            acc1 = __builtin_amdgcn_mfma_f32_32x32x16_bf16(av, bv1, acc1, 0, 0, 0);
          }
        }
        __builtin_amdgcn_s_setprio(0);
        // epilogue: bias1 + tanh -> h1 (cols 0..61 valid)
        const int hb = H1S0 + (i & 1) * HBUF;
#pragma unroll
        for (int p = 0; p < 2; ++p) {
          const f32x16 acc = p ? acc1 : acc0;
          int s = p * 32 + lrow;
          if (s < 62) {
            int wb2 = hb + s * 256;
            int wz = (s & 15) << 4;
#pragma unroll
            for (int qd = 0; qd < 4; ++qd) {
              int k0 = kt * 32 + qd * 8 + hi5 * 4;   // C rows: (reg&3)+8*(reg>>2)+4*hi
              float4 bq = *(const float4*)(lds + B1_OFF + k0 * 4);
              bf16x4 hv;
              hv[0] = (__bf16)fast_tanh(acc[qd * 4 + 0] + bq.x);
              hv[1] = (__bf16)fast_tanh(acc[qd * 4 + 1] + bq.y);
              hv[2] = (__bf16)fast_tanh(acc[qd * 4 + 2] + bq.z);
              hv[3] = (__bf16)fast_tanh(acc[qd * 4 + 3] + bq.w);
              *(bf16x4*)(lds + wb2 + ((k0 * 2) ^ wz)) = hv;
            }
          }
        }
      }
    } else {
      // ---- conv2 wave: consume h1 window i-1 (2 panels) from h1buf[(i&1)^1] ----
      if (i >= 1) {
        const int hb = H1S0 + ((i & 1) ^ 1) * HBUF;
        f32x16 acc0, acc1;
#pragma unroll
        for (int r = 0; r < 16; ++r) { acc0[r] = 0.f; acc1[r] = 0.f; }
        __builtin_amdgcn_s_setprio(1);
#pragma unroll
        for (int f = 0; f < 2; ++f) {
          int sv0 = lrow + f;                              // <= 33
          int sv1 = 32 + lrow + f; if (sv1 > 61) sv1 = 61;
          int b0 = hb + sv0 * 256, z0 = (sv0 & 15) << 4;
          int b1 = hb + sv1 * 256, z1 = (sv1 & 15) << 4;
#pragma unroll
          for (int kk = 0; kk < 8; ++kk) {
            int ko = kk * 32 + hi16;
            bf16x8 bv0 = __builtin_bit_cast(bf16x8,
                *(const u16x8*)(lds + b0 + (ko ^ z0)));
            acc0 = __builtin_amdgcn_mfma_f32_32x32x16_bf16(ap[f * 8 + kk], bv0, acc0, 0, 0, 0);
            bf16x8 bv1 = __builtin_bit_cast(bf16x8,
                *(const u16x8*)(lds + b1 + (ko ^ z1)));
            acc1 = __builtin_amdgcn_mfma_f32_32x32x16_bf16(ap[f * 8 + kk], bv1, acc1, 0, 0, 0);
          }
        }
        {   // tap 2 transient
          int sv0 = lrow + 2;
          int sv1 = 32 + lrow + 2; if (sv1 > 61) sv1 = 61;
          int b0 = hb + sv0 * 256, z0 = (sv0 & 15) << 4;
          int b1 = hb + sv1 * 256, z1 = (sv1 & 15) << 4;
#pragma unroll
          for (int kk = 0; kk < 8; ++kk) {
            bf16x8 av = __builtin_bit_cast(bf16x8,
                *(const u16x8*)(wfb + 2 * 16384 + kk * 2048));
            int ko = kk * 32 + hi16;
            bf16x8 bv0 = __builtin_bit_cast(bf16x8,
                *(const u16x8*)(lds + b0 + (ko ^ z0)));
            acc0 = __builtin_amdgcn_mfma_f32_32x32x16_bf16(av, bv0, acc0, 0, 0, 0);
            bf16x8 bv1 = __builtin_bit_cast(bf16x8,
                *(const u16x8*)(lds + b1 + (ko ^ z1)));
            acc1 = __builtin_amdgcn_mfma_f32_32x32x16_bf16(av, bv1, acc1, 0, 0, 0);
          }
        }
        __builtin_amdgcn_s_setprio(0);
        // epilogue: running PRE-TANH max, both panels fold into vmax[16]
        const int base = (i - 1) * YS;
        const bool valid0 = (base + lrow < TOUT);            // lrow < 60 always
        const int s2b = 32 + lrow;
        const bool valid1 = (s2b < YS) && (base + s2b < TOUT);
#pragma unroll
        for (int r = 0; r < 16; ++r) {
          float v0 = valid0 ? acc0[r] : -1e30f;
          float v1 = valid1 ? acc1[r] : -1e30f;
          vmax[r] = fmaxf(vmax[r], fmaxf(v0, v1));
        }
      }
    }

    // ---- convert + write staged X window i+1 into Xbuf[(i+1)&1] ----
    if (doStage) {
      const int xbn = XS0 + ((i + 1) & 1) * XBUF;
#pragma unroll
      for (int u = 0; u < 2; ++u) {
        int sl = slot_s + u * 32;
        const float* f0 = (const float*)&va[2 * u];
        bf16x8 o;
#pragma unroll
        for (int j = 0; j < 8; ++j) o[j] = (__bf16)f0[j];
        *(bf16x8*)(lds + xbn + sl * 256 + ((d0_s * 2) ^ ((sl & 15) << 4))) = o;
      }
    }
    __syncthreads();
  }

  // ---- final: conv2 waves reduce vmax across their 32 columns ----
  if (role == 1) {
#pragma unroll
    for (int r = 0; r < 16; ++r) {
      float v = vmax[r];
      v = fmaxf(v, __shfl_xor(v, 1, 64));
      v = fmaxf(v, __shfl_xor(v, 2, 64));
      v = fmaxf(v, __shfl_xor(v, 4, 64));
      v = fmaxf(v, __shfl_xor(v, 8, 64));
      v = fmaxf(v, __shfl_xor(v, 16, 64));
      vmax[r] = v;
    }
  }
  float* hbuf = (float*)(lds + XS0);   // X buffers dead now
  if (role == 1 && lrow == 0) {
#pragma unroll
    for (int r = 0; r < 16; ++r) {
      int rl = (r & 3) + 8 * (r >> 2) + 4 * hi5;
      hbuf[kt * 32 + rl] = vmax[r];
    }
  }
  __syncthreads();

  // ---- fused k2: bias2 + tanh, then 64x128 projection + tanh -> s_out ----
  float* htan = hbuf + 128;
  if (tid < 128) {
    const float* b2 = branch ? db2 : qb2;
    htan[tid] = fast_tanh(hbuf[tid] + b2[tid]);
  }
  __syncthreads();
  if (tid < 64) {
    const float* sw = branch ? dsw : qsw;
    const float* sb = branch ? dsb : qsb;
    float acc = sb[tid];
#pragma unroll
    for (int k = 0; k < 128; k += 4) {
      float4 wv = *(const float4*)(sw + tid * 128 + k);
      acc += htan[k] * wv.x + htan[k + 1] * wv.y + htan[k + 2] * wv.z + htan[k + 3] * wv.w;
    }
    s_out[(size_t)seq * 64 + tid] = fast_tanh(acc);
  }
}

// ---------------- k3: dots, gamma, softmax ----------------
__global__ void k3_softmax(const float* __restrict__ s_out,
                           const float* __restrict__ gw, const float* __restrict__ gb,
                           float* __restrict__ out) {
  int b = threadIdx.x;   // 64
  const float* qs = s_out + (size_t)b * 64;
  const float* ps = s_out + (size_t)(64 + b) * 64;
  const float* n0 = s_out + (size_t)(128 + b) * 64;
  const float* n1 = s_out + (size_t)(192 + b) * 64;
  float d0 = 0.f, d1 = 0.f, d2 = 0.f;
  for (int l = 0; l < 64; ++l) {
    float v = qs[l];
    d0 += v * ps[l];
    d1 += v * n0[l];
    d2 += v * n1[l];
  }
  float g = gw[0], bb = gb[0];
  d0 = g * d0 + bb; d1 = g * d1 + bb; d2 = g * d2 + bb;
  float m = fmaxf(d0, fmaxf(d1, d2));
  float e0 = expf(d0 - m), e1 = expf(d1 - m), e2 = expf(d2 - m);
  float inv = 1.0f / (e0 + e1 + e2);
  out[b * 3 + 0] = e0 * inv;
  out[b * 3 + 1] = e1 * inv;
  out[b * 3 + 2] = e2 * inv;
}

extern "C" void kernel_launch(void* const* d_in, const int* in_sizes, int n_in,
                              void* d_out, int out_size, void* d_ws, size_t ws_size,
                              hipStream_t stream) {
  const float* q    = (const float*)d_in[0];
  const float* pos  = (const float*)d_in[1];
  const float* negs = (const float*)d_in[2];
  const float* qw1  = (const float*)d_in[3];
  const float* qb1  = (const float*)d_in[4];
  const float* qw2  = (const float*)d_in[5];
  const float* qb2  = (const float*)d_in[6];
  const float* qsw  = (const float*)d_in[7];
  const float* qsb  = (const float*)d_in[8];
  const float* dw1  = (const float*)d_in[9];
  const float* db1  = (const float*)d_in[10];
  const float* dw2  = (const float*)d_in[11];
  const float* db2  = (const float*)d_in[12];
  const float* dsw  = (const float*)d_in[13];
  const float* dsb  = (const float*)d_in[14];
  const float* gw   = (const float*)d_in[15];
  const float* gb   = (const float*)d_in[16];
  float* out = (float*)d_out;

  char* ws = (char*)d_ws;
  unsigned short* W1f = (unsigned short*)(ws);             // 98304 elems = 196608 B
  unsigned short* W2f = (unsigned short*)(ws + 196608);    // 98304 elems = 196608 B
  float* s_out        = (float*)(ws + 393216);             // 256*64*4 = 65536 B

  hipFuncSetAttribute((const void*)cdssm_main,
                      hipFuncAttributeMaxDynamicSharedMemorySize, LDS_TOTAL);

  prep_kernel<<<768, 256, 0, stream>>>(qw1, qw2, dw1, dw2, W1f, W2f);
  cdssm_main<<<256, 512, LDS_TOTAL, stream>>>(q, pos, negs, W1f, W2f, qb1, db1,
                                              qb2, db2, qsw, qsb, dsw, dsb, s_out);
  k3_softmax<<<1, 64, 0, stream>>>(s_out, gw, gb, out);
}